// Round 4
// baseline (28001.785 us; speedup 1.0000x reference)
//
#include <hip/hip_runtime.h>
#include <hip/hip_bf16.h>

#define Bn 8
#define Hh 256
#define Ww 256
#define HW 65536
#define SDIM 64
#define LABELS 35
#define NHID 128

static inline __device__ float b2f(__hip_bfloat16 x) { return __bfloat162float(x); }

// ---------------- weight prep: f32 [O][I][9] -> f32 [O][ICP][9], ic zero-pad
__global__ void prep_w(const float* __restrict__ src, float* __restrict__ dst,
                       int OC, int IC, int ICP) {
    int n = OC * ICP * 9;
    for (int idx = blockIdx.x * blockDim.x + threadIdx.x; idx < n; idx += gridDim.x * blockDim.x) {
        int oc = idx / (ICP * 9);
        int r  = idx % (ICP * 9);
        int ic = r / 9;
        int k  = r % 9;
        float v = 0.f;
        if (ic < IC) v = src[(oc * IC + ic) * 9 + k];
        dst[idx] = v;
    }
}

// ---------------- fused conv1(64->64,lrelu) + masked class pooling ----------
__global__ __launch_bounds__(256) void conv1_pool_kernel(
    const float* __restrict__ in,             // [B][64][H][W]
    const float* __restrict__ wf,             // [64][64][9]
    const float* __restrict__ bf,             // [64]
    const int* __restrict__ seg, const float* __restrict__ bg,
    const float* __restrict__ mask,
    float* __restrict__ sums, int* __restrict__ cnts)
{
    __shared__ float tile[8][3][Ww + 2];
    __shared__ float s35[LABELS * 16];
    __shared__ int   c35[LABELS];

    const int t = threadIdx.x, h = blockIdx.y, b = blockIdx.z, ocb = blockIdx.x * 16;
    for (int i = t; i < LABELS * 16; i += 256) s35[i] = 0.f;
    if (t < LABELS) c35[t] = 0;

    float acc[16];
#pragma unroll
    for (int i = 0; i < 16; i++) acc[i] = bf[ocb + i];

    const float* inb = in + (size_t)b * 64 * HW;
    for (int icc = 0; icc < 64; icc += 8) {
        for (int i = t; i < 8 * 3 * (Ww + 2); i += 256) {
            int ic  = i / (3 * (Ww + 2));
            int rem = i % (3 * (Ww + 2));
            int r = rem / (Ww + 2), x = rem % (Ww + 2);
            int gh = h + r - 1, gw = x - 1;
            float v = 0.f;
            if ((unsigned)gh < Hh && (unsigned)gw < Ww)
                v = inb[(size_t)(icc + ic) * HW + gh * Ww + gw];
            tile[ic][r][x] = v;
        }
        __syncthreads();
#pragma unroll
        for (int ic = 0; ic < 8; ++ic) {
            float v[9];
#pragma unroll
            for (int ky = 0; ky < 3; ky++)
#pragma unroll
                for (int kx = 0; kx < 3; kx++) v[ky * 3 + kx] = tile[ic][ky][t + kx];
#pragma unroll
            for (int oc = 0; oc < 16; oc++) {
                const float* wp = wf + ((size_t)(ocb + oc) * 64 + icc + ic) * 9;
#pragma unroll
                for (int k = 0; k < 9; k++) acc[oc] = fmaf(v[k], wp[k], acc[oc]);
            }
        }
        __syncthreads();
    }

    // lrelu + masked pooling
    int p = h * Ww + t;
    int lab = seg[(size_t)b * HW + p];
    bool m = (bg[(size_t)b * HW + p] != 0.f) && (mask[(size_t)b * HW + p] == 0.f);
#pragma unroll
    for (int oc = 0; oc < 16; oc++) {
        float o = acc[oc];
        acc[oc] = (o >= 0.f) ? o : 0.2f * o;
    }
    if (m) {
#pragma unroll
        for (int oc = 0; oc < 16; oc++) atomicAdd(&s35[lab * 16 + oc], acc[oc]);
        if (blockIdx.x == 0) atomicAdd(&c35[lab], 1);
    }
    __syncthreads();
    for (int i = t; i < LABELS * 16; i += 256) {
        int s = i >> 4, oc = i & 15;
        float v = s35[i];
        if (v != 0.f) atomicAdd(&sums[((size_t)b * LABELS + s) * SDIM + ocb + oc], v);
    }
    if (blockIdx.x == 0 && t < LABELS && c35[t] > 0) atomicAdd(&cnts[b * LABELS + t], c35[t]);
}

// ---------------- codes = keep * where(cnt>0, sums/cnt, 0) ------------------
__global__ void codes_kernel(const float* __restrict__ sums, const int* __restrict__ cnts,
                             float* __restrict__ codes) {
    int idx = blockIdx.x * blockDim.x + threadIdx.x;
    if (idx >= Bn * LABELS * SDIM) return;
    int s  = (idx >> 6) % LABELS;
    int bs = idx >> 6;
    int cnt = cnts[bs];
    bool keep = !(s >= 24 && s <= 33);
    codes[idx] = (cnt > 0 && keep) ? sums[idx] / (float)cnt : 0.f;
}

// ---------------- conv_c0 pass 1: per-channel sum / sumsq -------------------
__global__ __launch_bounds__(256) void conv_c0_stats_kernel(
    const float* __restrict__ in, const float* __restrict__ wf,
    const float* __restrict__ bf, float* __restrict__ statacc)
{
    __shared__ float tile[8][3][Ww + 2];
    __shared__ float wsum[4][16][2];
    const int t = threadIdx.x, h = blockIdx.y, b = blockIdx.z, ocb = blockIdx.x * 16;

    float acc[16];
#pragma unroll
    for (int i = 0; i < 16; i++) acc[i] = bf[ocb + i];

    const float* inb = in + (size_t)b * 64 * HW;
    for (int icc = 0; icc < 64; icc += 8) {
        for (int i = t; i < 8 * 3 * (Ww + 2); i += 256) {
            int ic  = i / (3 * (Ww + 2));
            int rem = i % (3 * (Ww + 2));
            int r = rem / (Ww + 2), x = rem % (Ww + 2);
            int gh = h + r - 1, gw = x - 1;
            float v = 0.f;
            if ((unsigned)gh < Hh && (unsigned)gw < Ww)
                v = inb[(size_t)(icc + ic) * HW + gh * Ww + gw];
            tile[ic][r][x] = v;
        }
        __syncthreads();
#pragma unroll
        for (int ic = 0; ic < 8; ++ic) {
            float v[9];
#pragma unroll
            for (int ky = 0; ky < 3; ky++)
#pragma unroll
                for (int kx = 0; kx < 3; kx++) v[ky * 3 + kx] = tile[ic][ky][t + kx];
#pragma unroll
            for (int oc = 0; oc < 16; oc++) {
                const float* wp = wf + ((size_t)(ocb + oc) * 64 + icc + ic) * 9;
#pragma unroll
                for (int k = 0; k < 9; k++) acc[oc] = fmaf(v[k], wp[k], acc[oc]);
            }
        }
        __syncthreads();
    }

    int lane = t & 63, w = t >> 6;
#pragma unroll
    for (int oc = 0; oc < 16; oc++) {
        float s = acc[oc], ss = acc[oc] * acc[oc];
#pragma unroll
        for (int off = 32; off > 0; off >>= 1) { s += __shfl_down(s, off); ss += __shfl_down(ss, off); }
        if (lane == 0) { wsum[w][oc][0] = s; wsum[w][oc][1] = ss; }
    }
    __syncthreads();
    if (t < 16) {
        float S = 0.f, SS = 0.f;
#pragma unroll
        for (int w2 = 0; w2 < 4; w2++) { S += wsum[w2][t][0]; SS += wsum[w2][t][1]; }
        atomicAdd(&statacc[(size_t)(b * SDIM + ocb + t) * 2 + 0], S);
        atomicAdd(&statacc[(size_t)(b * SDIM + ocb + t) * 2 + 1], SS);
    }
}

__global__ void finalize_stats(const float* __restrict__ statacc,
                               float* __restrict__ mu, float* __restrict__ rsig) {
    int i = blockIdx.x * blockDim.x + threadIdx.x;
    if (i >= Bn * SDIM) return;
    float S = statacc[2 * i], SS = statacc[2 * i + 1];
    float m = S / (float)HW;
    float v = SS / (float)HW - m * m;
    mu[i] = m;
    rsig[i] = rsqrtf(v + 1e-5f);
}

// ---------------- conv_sh with out_map generated on the fly -----------------
// input channels: 0..63 style (codes[lab][f]*bg), 64..98 seg one-hot*bg, 99..103 zero
__global__ __launch_bounds__(256) void conv_sh_kernel(
    const int* __restrict__ seg_b, const float* __restrict__ bg_b,
    const float* __restrict__ codes_b,        // [35*64]
    const float* __restrict__ wf,             // [128][104][9]
    const float* __restrict__ bf,             // [128]
    __hip_bfloat16* __restrict__ actv)        // [128][HW]
{
    __shared__ float tile[8][3 * (Ww + 2)];
    __shared__ float cod[LABELS * SDIM];
    __shared__ int   labrow[3 * (Ww + 2)];
    __shared__ float bgrow[3 * (Ww + 2)];

    const int t = threadIdx.x, h = blockIdx.y, ocb = blockIdx.x * 16;

    for (int i = t; i < LABELS * SDIM; i += 256) cod[i] = codes_b[i];
    for (int i = t; i < 3 * (Ww + 2); i += 256) {
        int r = i / (Ww + 2), x = i % (Ww + 2);
        int gh = h + r - 1, gw = x - 1;
        int lab = 0; float bgv = 0.f;
        if ((unsigned)gh < Hh && (unsigned)gw < Ww) {
            lab = seg_b[gh * Ww + gw];
            bgv = bg_b[gh * Ww + gw];
        }
        labrow[i] = lab; bgrow[i] = bgv;
    }

    float acc[16];
#pragma unroll
    for (int i = 0; i < 16; i++) acc[i] = bf[ocb + i];
    __syncthreads();

    for (int icc = 0; icc < 104; icc += 8) {
        for (int i = t; i < 8 * 3 * (Ww + 2); i += 256) {
            int ic  = i / (3 * (Ww + 2));
            int rem = i % (3 * (Ww + 2));
            int gic = icc + ic;
            int lab = labrow[rem]; float bgv = bgrow[rem];
            float v;
            if (gic < 64)      v = cod[lab * SDIM + gic] * bgv;
            else if (gic < 99) v = ((gic - 64) == lab) ? bgv : 0.f;
            else               v = 0.f;
            tile[ic][rem] = v;
        }
        __syncthreads();
#pragma unroll
        for (int ic = 0; ic < 8; ++ic) {
            float v[9];
#pragma unroll
            for (int ky = 0; ky < 3; ky++)
#pragma unroll
                for (int kx = 0; kx < 3; kx++) v[ky * 3 + kx] = tile[ic][ky * (Ww + 2) + t + kx];
#pragma unroll
            for (int oc = 0; oc < 16; oc++) {
                const float* wp = wf + ((size_t)(ocb + oc) * 104 + icc + ic) * 9;
#pragma unroll
                for (int k = 0; k < 9; k++) acc[oc] = fmaf(v[k], wp[k], acc[oc]);
            }
        }
        __syncthreads();
    }

#pragma unroll
    for (int oc = 0; oc < 16; oc++) {
        float o = fmaxf(acc[oc], 0.f);   // relu
        actv[(size_t)(ocb + oc) * HW + h * Ww + t] = __float2bfloat16(o);
    }
}

// ---------------- fused: dx=conv_c0, gamma/beta convs, IN + lrelu -----------
__global__ __launch_bounds__(256) void final_fused_kernel(
    const float* __restrict__ fin_b,            // featmap_in + b*64*HW
    const __hip_bfloat16* __restrict__ actv,    // [128][HW]
    const float* __restrict__ wf_c0, const float* __restrict__ bf_c0,
    const float* __restrict__ wf_g,  const float* __restrict__ bf_g,
    const float* __restrict__ wf_b2, const float* __restrict__ bf_b2,
    const float* __restrict__ mu_b, const float* __restrict__ rsig_b,
    float* __restrict__ out_b)
{
    __shared__ float tile[8][3 * (Ww + 2)];
    const int t = threadIdx.x, h = blockIdx.y, ocb = blockIdx.x * 16;

    float ad[16], ag[16], ab[16];
#pragma unroll
    for (int i = 0; i < 16; i++) { ad[i] = bf_c0[ocb + i]; ag[i] = bf_g[ocb + i]; ab[i] = bf_b2[ocb + i]; }

    // pass 1: dx = conv_c0(featmap_in)
    for (int icc = 0; icc < 64; icc += 8) {
        for (int i = t; i < 8 * 3 * (Ww + 2); i += 256) {
            int ic  = i / (3 * (Ww + 2));
            int rem = i % (3 * (Ww + 2));
            int r = rem / (Ww + 2), x = rem % (Ww + 2);
            int gh = h + r - 1, gw = x - 1;
            float v = 0.f;
            if ((unsigned)gh < Hh && (unsigned)gw < Ww)
                v = fin_b[(size_t)(icc + ic) * HW + gh * Ww + gw];
            tile[ic][rem] = v;
        }
        __syncthreads();
#pragma unroll
        for (int ic = 0; ic < 8; ++ic) {
            float v[9];
#pragma unroll
            for (int ky = 0; ky < 3; ky++)
#pragma unroll
                for (int kx = 0; kx < 3; kx++) v[ky * 3 + kx] = tile[ic][ky * (Ww + 2) + t + kx];
#pragma unroll
            for (int oc = 0; oc < 16; oc++) {
                const float* wp = wf_c0 + ((size_t)(ocb + oc) * 64 + icc + ic) * 9;
#pragma unroll
                for (int k = 0; k < 9; k++) ad[oc] = fmaf(v[k], wp[k], ad[oc]);
            }
        }
        __syncthreads();
    }

    // pass 2: gamma/beta convs over actv
    for (int icc = 0; icc < 128; icc += 8) {
        for (int i = t; i < 8 * 3 * (Ww + 2); i += 256) {
            int ic  = i / (3 * (Ww + 2));
            int rem = i % (3 * (Ww + 2));
            int r = rem / (Ww + 2), x = rem % (Ww + 2);
            int gh = h + r - 1, gw = x - 1;
            float v = 0.f;
            if ((unsigned)gh < Hh && (unsigned)gw < Ww)
                v = b2f(actv[(size_t)(icc + ic) * HW + gh * Ww + gw]);
            tile[ic][rem] = v;
        }
        __syncthreads();
#pragma unroll
        for (int ic = 0; ic < 8; ++ic) {
            float v[9];
#pragma unroll
            for (int ky = 0; ky < 3; ky++)
#pragma unroll
                for (int kx = 0; kx < 3; kx++) v[ky * 3 + kx] = tile[ic][ky * (Ww + 2) + t + kx];
#pragma unroll
            for (int oc = 0; oc < 16; oc++) {
                const float* wpg = wf_g  + ((size_t)(ocb + oc) * 128 + icc + ic) * 9;
                const float* wpb = wf_b2 + ((size_t)(ocb + oc) * 128 + icc + ic) * 9;
#pragma unroll
                for (int k = 0; k < 9; k++) {
                    ag[oc] = fmaf(v[k], wpg[k], ag[oc]);
                    ab[oc] = fmaf(v[k], wpb[k], ab[oc]);
                }
            }
        }
        __syncthreads();
    }

#pragma unroll
    for (int oc = 0; oc < 16; oc++) {
        int c = ocb + oc;
        float nrm = (ad[oc] - mu_b[c]) * rsig_b[c];
        float o = nrm * (1.f + ag[oc]) + ab[oc];
        o = (o >= 0.f) ? o : 0.2f * o;
        out_b[(size_t)c * HW + h * Ww + t] = o;
    }
}

// ===========================================================================
extern "C" void kernel_launch(void* const* d_in, const int* in_sizes, int n_in,
                              void* d_out, int out_size, void* d_ws, size_t ws_size,
                              hipStream_t stream) {
    const float* featmap_in = (const float*)d_in[0];
    const int*   seg        = (const int*)d_in[1];
    const float* bg         = (const float*)d_in[2];
    const float* mask       = (const float*)d_in[3];
    const float* w_conv     = (const float*)d_in[4];
    const float* b_conv     = (const float*)d_in[5];
    const float* w_c0       = (const float*)d_in[6];
    const float* b_c0       = (const float*)d_in[7];
    const float* w_sh       = (const float*)d_in[8];
    const float* b_sh       = (const float*)d_in[9];
    const float* w_g        = (const float*)d_in[10];
    const float* b_g        = (const float*)d_in[11];
    const float* w_b        = (const float*)d_in[12];
    const float* b_b        = (const float*)d_in[13];
    float* out = (float*)d_out;

    // ---- workspace arena (total < 20 MB) ----
    char* ws = (char*)d_ws;
    size_t o = 0;
    auto alloc = [&](size_t bytes) { size_t r = o; o = (o + bytes + 255) & ~(size_t)255; return r; };

    float* wf_sh   = (float*)(ws + alloc(128 * 104 * 9 * 4));
    float* sums    = (float*)(ws + alloc(Bn * LABELS * SDIM * 4));
    int*   cnts    = (int*)(ws + alloc(Bn * LABELS * 4));
    float* codes   = (float*)(ws + alloc(Bn * LABELS * SDIM * 4));
    float* statacc = (float*)(ws + alloc(Bn * SDIM * 2 * 4));
    float* mu      = (float*)(ws + alloc(Bn * SDIM * 4));
    float* rsig    = (float*)(ws + alloc(Bn * SDIM * 4));
    __hip_bfloat16* actv = (__hip_bfloat16*)(ws + alloc((size_t)NHID * HW * 2));  // 16.8 MB

    // ---- weight prep: only w_sh needs ic zero-padding (99 -> 104) ----
    prep_w<<<468, 256, 0, stream>>>(w_sh, wf_sh, 128, 99, 104);

    hipMemsetAsync(sums, 0, Bn * LABELS * SDIM * 4, stream);
    hipMemsetAsync(cnts, 0, Bn * LABELS * 4, stream);
    hipMemsetAsync(statacc, 0, Bn * SDIM * 2 * 4, stream);

    // ---- fused conv1 + masked pooling ----
    conv1_pool_kernel<<<dim3(4, Hh, Bn), 256, 0, stream>>>(
        featmap_in, w_conv, b_conv, seg, bg, mask, sums, cnts);
    codes_kernel<<<(Bn * LABELS * SDIM + 255) / 256, 256, 0, stream>>>(sums, cnts, codes);

    // ---- conv_c0 stats pass ----
    conv_c0_stats_kernel<<<dim3(4, Hh, Bn), 256, 0, stream>>>(featmap_in, w_c0, b_c0, statacc);
    finalize_stats<<<2, 256, 0, stream>>>(statacc, mu, rsig);

    // ---- per-batch: conv_sh -> actv, then fused final ----
    for (int b = 0; b < Bn; b++) {
        conv_sh_kernel<<<dim3(8, Hh), 256, 0, stream>>>(
            seg + (size_t)b * HW, bg + (size_t)b * HW, codes + (size_t)b * LABELS * SDIM,
            wf_sh, b_sh, actv);
        final_fused_kernel<<<dim3(4, Hh), 256, 0, stream>>>(
            featmap_in + (size_t)b * 64 * HW, actv,
            w_c0, b_c0, w_g, b_g, w_b, b_b,
            mu + b * SDIM, rsig + b * SDIM,
            out + (size_t)b * SDIM * HW);
    }
}